// Round 1
// baseline (326.418 us; speedup 1.0000x reference)
//
#include <hip/hip_runtime.h>
#include <math.h>

// NeRF volume rendering: N=65536 rays, S=192 samples.
// One wave (64 lanes) per ray; 3 chunks of 64 samples each.
//
// v2: latency-bound fix (VALUBusy 26%, HBM 29%, occ 68% in v1):
//  - All cross-lane ops are DPP (row_shr / row_bcast15/31 / wf_shr1): pure
//    VALU, no ds_bpermute, no lgkmcnt stalls. gfx9/CDNA retains these ctrls
//    (RDNA dropped them); LLVM's own atomic-optimizer emits them on gfx9xx.
//  - The 3 chunk scans run INDEPENDENTLY (ILP=3); inter-chunk carry is
//    combined afterwards via v_readlane scalars: carry = {1, t0, t0*t1}
//    (identical fp association to the old serial carry).
//  - All 18 global loads (6 z, 3 sigma, 9 rgb) hoisted into registers
//    up-front so they overlap the exp + scan work.

constexpr int kRays = 65536;
constexpr int kS = 192;

// ---- DPP cross-lane helpers (all VALU; zero DS ops) ----
// __builtin_amdgcn_update_dpp(old, src, dpp_ctrl, row_mask, bank_mask, bound_ctrl)
// lanes disabled by row_mask / with no source (bound_ctrl=false) receive `old`.
template <int CTRL, int RMASK>
__device__ __forceinline__ float dpp_mul(float v) {
    const int t = __builtin_amdgcn_update_dpp(0x3f800000 /*1.0f*/, __float_as_int(v),
                                              CTRL, RMASK, 0xF, false);
    return v * __int_as_float(t);
}
template <int CTRL, int RMASK>
__device__ __forceinline__ float dpp_add(float v) {
    const int t = __builtin_amdgcn_update_dpp(0 /*0.0f*/, __float_as_int(v),
                                              CTRL, RMASK, 0xF, false);
    return v + __int_as_float(t);
}

// Inclusive 64-lane prefix product: Hillis-Steele within 16-lane rows
// (row_shr 1/2/4/8), then row_bcast15 -> rows 1,3 and row_bcast31 -> rows 2,3.
__device__ __forceinline__ float scan_mul64(float x) {
    float v = x;
    v = dpp_mul<0x111, 0xF>(v);   // row_shr:1
    v = dpp_mul<0x112, 0xF>(v);   // row_shr:2
    v = dpp_mul<0x114, 0xF>(v);   // row_shr:4
    v = dpp_mul<0x118, 0xF>(v);   // row_shr:8
    v = dpp_mul<0x142, 0xA>(v);   // row_bcast15 (rows 1,3)
    v = dpp_mul<0x143, 0xC>(v);   // row_bcast31 (rows 2,3)
    return v;
}

// 64-lane sum via the same pattern; total lands in lane 63.
__device__ __forceinline__ float red_add64(float x) {
    float v = x;
    v = dpp_add<0x111, 0xF>(v);
    v = dpp_add<0x112, 0xF>(v);
    v = dpp_add<0x114, 0xF>(v);
    v = dpp_add<0x118, 0xF>(v);
    v = dpp_add<0x142, 0xA>(v);
    v = dpp_add<0x143, 0xC>(v);
    return v;
}

__global__ __launch_bounds__(256) void nerf_render_kernel(
    const float* __restrict__ rgb,      // [N, S, 3]
    const float* __restrict__ sigma,    // [N, S]
    const float* __restrict__ z_vals,   // [N, S]
    const float* __restrict__ rays_d,   // [N, 3]
    float* __restrict__ out)
{
    const int lane = threadIdx.x & 63;
    const int ray  = (blockIdx.x << 2) + (threadIdx.x >> 6);  // 4 waves/block

    float* __restrict__ rgb_map   = out;                                        // [N,3]
    float* __restrict__ depth_map = out + (size_t)kRays * 3;                    // [N]
    float* __restrict__ acc_map   = out + (size_t)kRays * 4;                    // [N]
    float* __restrict__ weights_o = out + (size_t)kRays * 5;                    // [N,S]
    float* __restrict__ disp_map  = out + (size_t)kRays * 5 + (size_t)kRays * kS;      // [N]
    float* __restrict__ trans_o   = out + (size_t)kRays * 6 + (size_t)kRays * kS;      // [N,S]
    float* __restrict__ alpha_o   = out + (size_t)kRays * 6 + (size_t)kRays * kS * 2;  // [N,S]

    const float dx = rays_d[ray * 3 + 0];
    const float dy = rays_d[ray * 3 + 1];
    const float dz = rays_d[ray * 3 + 2];
    const float nrm = sqrtf(dx * dx + dy * dy + dz * dz);

    const size_t base = (size_t)ray * kS;

    // ---- load phase: issue ALL global loads up-front (18 per lane) ----
    float zc[3], zn[3], sg[3], cr[3], cg[3], cb[3];
    #pragma unroll
    for (int c = 0; c < 3; ++c) {
        const int idx  = c * 64 + lane;
        const int nidx = (idx + 1 < kS) ? idx + 1 : kS - 1;  // clamp: lane 63 of chunk 2
        zc[c] = z_vals[base + idx];
        zn[c] = z_vals[base + nidx];
        sg[c] = sigma[base + idx];
        const size_t rb = (base + idx) * 3;
        cr[c] = rgb[rb + 0];
        cg[c] = rgb[rb + 1];
        cb[c] = rgb[rb + 2];
    }

    // ---- alpha + three INDEPENDENT prefix-product scans (ILP = 3) ----
    float alpha[3], p[3];
    #pragma unroll
    for (int c = 0; c < 3; ++c) {
        const int idx = c * 64 + lane;
        const float dist = (idx < kS - 1) ? (zn[c] - zc[c]) * nrm : 1e10f * nrm;
        float s = sg[c] > 0.f ? sg[c] : 0.f;           // relu
        const float e = expf(-s * dist);
        alpha[c] = 1.0f - e;
        const float om = 1.0f - alpha[c];              // match reference rounding
        p[c] = scan_mul64(om);                         // inclusive prefix product
    }

    // ---- chunk totals (scalar) + exclusive shift, then combine carries ----
    float tot[3], excl[3];
    #pragma unroll
    for (int c = 0; c < 3; ++c) {
        tot[c] = __int_as_float(__builtin_amdgcn_readlane(__float_as_int(p[c]), 63));
        // wf_shr:1 = whole-wave shift toward higher lanes; lane 0 gets old=1.0
        const int t = __builtin_amdgcn_update_dpp(0x3f800000, __float_as_int(p[c]),
                                                  0x138, 0xF, 0xF, false);
        excl[c] = __int_as_float(t);
    }
    const float carry1 = tot[0];
    const float carry2 = tot[0] * tot[1];   // same association as old serial carry

    // ---- weights, stores, per-ray partial sums ----
    float sr = 0.f, sg_ = 0.f, sb = 0.f, sd = 0.f, sw = 0.f;
    #pragma unroll
    for (int c = 0; c < 3; ++c) {
        const int idx = c * 64 + lane;
        const float carry = (c == 0) ? 1.0f : ((c == 1) ? carry1 : carry2);
        const float trans = carry * excl[c];
        const float w = alpha[c] * trans;

        trans_o[base + idx]   = trans;
        alpha_o[base + idx]   = alpha[c];
        weights_o[base + idx] = w;

        sr  += w * cr[c];
        sg_ += w * cg[c];
        sb  += w * cb[c];
        sd  += w * zc[c];
        sw  += w;
    }

    // ---- 5 per-ray reductions, all-DPP; totals land in lane 63 ----
    sr  = red_add64(sr);
    sg_ = red_add64(sg_);
    sb  = red_add64(sb);
    sd  = red_add64(sd);
    sw  = red_add64(sw);

    if (lane == 63) {
        rgb_map[ray * 3 + 0] = sr;
        rgb_map[ray * 3 + 1] = sg_;
        rgb_map[ray * 3 + 2] = sb;
        depth_map[ray] = sd;
        acc_map[ray]   = sw;
        const float q = fmaxf(1e-10f, sd / sw);
        disp_map[ray] = 1.0f / q;
    }
}

extern "C" void kernel_launch(void* const* d_in, const int* in_sizes, int n_in,
                              void* d_out, int out_size, void* d_ws, size_t ws_size,
                              hipStream_t stream) {
    const float* rgb    = (const float*)d_in[0];
    const float* sigma  = (const float*)d_in[1];
    const float* z_vals = (const float*)d_in[2];
    const float* rays_d = (const float*)d_in[3];
    float* out = (float*)d_out;

    const int blocks = kRays / 4;  // 4 rays (waves) per 256-thread block
    nerf_render_kernel<<<blocks, 256, 0, stream>>>(rgb, sigma, z_vals, rays_d, out);
}